// Round 1
// baseline (1910.575 us; speedup 1.0000x reference)
//
#include <hip/hip_runtime.h>
#include <hip/hip_bf16.h>
#include <math.h>

// Problem constants
#define NB    128        // batch
#define NTOK  196        // tokens
#define DIMC  768        // channels
#define AGN   4          // agent tokens
#define SCALE_F 0.036084391824351614f   // 1/sqrt(768)

// ---------------------------------------------------------------------------
// Tiled SGEMM: C[M,N] = A[M,K] @ B[K,N] (+bias) (+gelu)
// BM=BN=128, BK=16, 256 threads, 8x8 per thread.
// EPI: 0 = none, 1 = +bias, 2 = +bias then exact-erf GELU
// ---------------------------------------------------------------------------
template<int EPI>
__global__ __launch_bounds__(256, 2) void sgemm_k(
    const float* __restrict__ A, int lda,
    const float* __restrict__ B, int ldb,
    const float* __restrict__ bias,
    float* __restrict__ C, int ldc, int K)
{
    __shared__ float As[16][132];   // A tile transposed: As[k][m], padded stride
    __shared__ float Bs[16][128];   // B tile natural:    Bs[k][n]

    const int tid = threadIdx.x;
    const int row0 = blockIdx.y * 128;
    const int col0 = blockIdx.x * 128;
    const int tx = tid & 15;        // 16 col-threads
    const int ty = tid >> 4;        // 16 row-threads

    float acc[8][8];
    #pragma unroll
    for (int i = 0; i < 8; i++)
        #pragma unroll
        for (int j = 0; j < 8; j++) acc[i][j] = 0.f;

    const int ar = tid >> 2;            // A load: rows ar, ar+64
    const int ac = (tid & 3) * 4;       // k-offset within tile
    const int br = tid >> 5;            // B load: rows br, br+8
    const int bc = (tid & 31) * 4;      // col offset
    const float* Aptr = A + (size_t)(row0 + ar) * lda + ac;
    const float* Bptr = B + (size_t)br * ldb + col0 + bc;

    for (int bk = 0; bk < K; bk += 16) {
        float4 a0 = *(const float4*)(Aptr + bk);
        float4 a1 = *(const float4*)(Aptr + (size_t)64 * lda + bk);
        float4 b0 = *(const float4*)(Bptr + (size_t)bk * ldb);
        float4 b1 = *(const float4*)(Bptr + (size_t)(bk + 8) * ldb);

        __syncthreads();   // previous iter's LDS reads done
        As[ac+0][ar] = a0.x; As[ac+1][ar] = a0.y; As[ac+2][ar] = a0.z; As[ac+3][ar] = a0.w;
        As[ac+0][ar+64] = a1.x; As[ac+1][ar+64] = a1.y; As[ac+2][ar+64] = a1.z; As[ac+3][ar+64] = a1.w;
        *(float4*)&Bs[br][bc]     = b0;
        *(float4*)&Bs[br+8][bc]   = b1;
        __syncthreads();

        #pragma unroll
        for (int k = 0; k < 16; k++) {
            float4 aA = *(const float4*)&As[k][ty*8];
            float4 aB = *(const float4*)&As[k][ty*8 + 4];
            float4 bA = *(const float4*)&Bs[k][tx*8];
            float4 bB = *(const float4*)&Bs[k][tx*8 + 4];
            float av[8] = {aA.x,aA.y,aA.z,aA.w,aB.x,aB.y,aB.z,aB.w};
            float bv[8] = {bA.x,bA.y,bA.z,bA.w,bB.x,bB.y,bB.z,bB.w};
            #pragma unroll
            for (int i = 0; i < 8; i++)
                #pragma unroll
                for (int j = 0; j < 8; j++)
                    acc[i][j] = fmaf(av[i], bv[j], acc[i][j]);
        }
    }

    float bvals[8];
    #pragma unroll
    for (int j = 0; j < 8; j++)
        bvals[j] = (EPI > 0) ? bias[col0 + tx*8 + j] : 0.f;

    #pragma unroll
    for (int i = 0; i < 8; i++) {
        float* cp = C + (size_t)(row0 + ty*8 + i) * ldc + col0 + tx*8;
        float vals[8];
        #pragma unroll
        for (int j = 0; j < 8; j++) {
            float v = acc[i][j];
            if (EPI > 0) v += bvals[j];
            if (EPI == 2) v = 0.5f * v * (1.f + erff(v * 0.7071067811865476f));
            vals[j] = v;
        }
        *(float4*)(cp)     = make_float4(vals[0], vals[1], vals[2], vals[3]);
        *(float4*)(cp + 4) = make_float4(vals[4], vals[5], vals[6], vals[7]);
    }
}

// ---------------------------------------------------------------------------
// Mean over tokens: mh[b][j] = mean_n h1[b,n,j]   (h1: [B*N, 384])
// ---------------------------------------------------------------------------
__global__ __launch_bounds__(384) void mean_k(const float* __restrict__ h1,
                                              float* __restrict__ mh)
{
    const int b = blockIdx.x, j = threadIdx.x;
    const float* p = h1 + (size_t)b * NTOK * 384 + j;
    float s = 0.f;
    for (int n = 0; n < NTOK; n++) s += p[(size_t)n * 384];
    mh[b * 384 + j] = s * (1.f / (float)NTOK);
}

// ---------------------------------------------------------------------------
// agent_base[b][j] = mh[b,:] @ W2[:,j] + b2[j]   (j in [0,3072))
// grid (12 j-chunks, 16 b-chunks of 8), 256 threads
// ---------------------------------------------------------------------------
__global__ __launch_bounds__(256) void pool2_k(const float* __restrict__ mh,
                                               const float* __restrict__ W2,
                                               const float* __restrict__ b2,
                                               float* __restrict__ ab)
{
    __shared__ float rows[8][384];
    const int tid = threadIdx.x;
    const int bb0 = blockIdx.y * 8;
    for (int i = tid; i < 8 * 384; i += 256)
        rows[i / 384][i % 384] = mh[(size_t)(bb0 + i / 384) * 384 + (i % 384)];
    __syncthreads();

    const int j = blockIdx.x * 256 + tid;
    const float bj = b2[j];
    float acc[8];
    #pragma unroll
    for (int r = 0; r < 8; r++) acc[r] = bj;
    for (int k = 0; k < 384; k++) {
        float w = W2[(size_t)k * 3072 + j];
        #pragma unroll
        for (int r = 0; r < 8; r++) acc[r] = fmaf(rows[r][k], w, acc[r]);
    }
    #pragma unroll
    for (int r = 0; r < 8; r++) ab[(size_t)(bb0 + r) * 3072 + j] = acc[r];
}

// ---------------------------------------------------------------------------
__device__ __forceinline__ float wred_max(float v) {
    #pragma unroll
    for (int o = 32; o; o >>= 1) v = fmaxf(v, __shfl_xor(v, o, 64));
    return v;
}
__device__ __forceinline__ float wred_sum(float v) {
    #pragma unroll
    for (int o = 32; o; o >>= 1) v += __shfl_xor(v, o, 64);
    return v;
}

// ---------------------------------------------------------------------------
// Stage 1 (one block per batch):
//  scores = softmax_n(SCALE * at @ k^T)  -> out_rep
//  pblend = scores * (softmax_n(attn1+attn2) + 2) / 3     [softmax over h==1 -> 1]
//  agent_v = pblend @ v
//  at_blend = at * (softmax_d(tk1+tk2) + 2) / 3 -> out_at, ws
// ---------------------------------------------------------------------------
__global__ __launch_bounds__(256) void stage1_k(
    const float* __restrict__ qkv, const float* __restrict__ agent_base,
    const float* __restrict__ attn1, const float* __restrict__ attn2,
    const float* __restrict__ tk1, const float* __restrict__ tk2,
    float* __restrict__ agent_v, float* __restrict__ at_blend,
    float* __restrict__ out_rep, float* __restrict__ out_at)
{
    __shared__ float at_s[AGN * DIMC];
    __shared__ float sc[AGN][NTOK];
    __shared__ float s2[AGN][NTOK];

    const int b = blockIdx.x, tid = threadIdx.x;
    for (int i = tid; i < AGN * DIMC; i += 256) at_s[i] = agent_base[(size_t)b * 3072 + i];
    __syncthreads();

    // scores: thread n computes 4 dots of length 768 against k rows
    if (tid < NTOK) {
        const float* krow = qkv + (size_t)(b * NTOK + tid) * 2304 + 768;
        float s[AGN] = {0.f, 0.f, 0.f, 0.f};
        for (int d = 0; d < DIMC; d += 4) {
            float4 kv = *(const float4*)(krow + d);
            #pragma unroll
            for (int a = 0; a < AGN; a++) {
                const float* ap = at_s + a * DIMC + d;
                s[a] += ap[0]*kv.x + ap[1]*kv.y + ap[2]*kv.z + ap[3]*kv.w;
            }
        }
        #pragma unroll
        for (int a = 0; a < AGN; a++) {
            sc[a][tid] = s[a] * SCALE_F;
            s2[a][tid] = attn1[(size_t)(b*AGN + a)*NTOK + tid] + attn2[(size_t)(b*AGN + a)*NTOK + tid];
        }
    }
    __syncthreads();

    // per-wave softmax over n (wave w handles agent a=w)
    const int w = tid >> 6, l = tid & 63;
    {
        const int a = w;
        float m = -1e30f;
        for (int i = l; i < NTOK; i += 64) m = fmaxf(m, sc[a][i]);
        m = wred_max(m);
        float ss = 0.f;
        for (int i = l; i < NTOK; i += 64) { float e = expf(sc[a][i] - m); sc[a][i] = e; ss += e; }
        ss = wred_sum(ss);
        float inv = 1.f / ss;
        for (int i = l; i < NTOK; i += 64) {
            float p = sc[a][i] * inv;
            sc[a][i] = p;
            out_rep[(size_t)(b*AGN + a)*NTOK + i] = p;
        }
        float m2 = -1e30f;
        for (int i = l; i < NTOK; i += 64) m2 = fmaxf(m2, s2[a][i]);
        m2 = wred_max(m2);
        float ss2 = 0.f;
        for (int i = l; i < NTOK; i += 64) { float e = expf(s2[a][i] - m2); s2[a][i] = e; ss2 += e; }
        ss2 = wred_sum(ss2);
        float inv2 = 1.f / ss2;
        for (int i = l; i < NTOK; i += 64)
            s2[a][i] = sc[a][i] * (s2[a][i] * inv2 + 2.f) * (1.f / 3.f);
    }
    __syncthreads();

    // agent_v[a][d] = sum_n pblend[a][n] * v[n][d]   (coalesced over d)
    for (int d = tid; d < DIMC; d += 256) {
        float av[AGN] = {0.f, 0.f, 0.f, 0.f};
        const float* vcol = qkv + (size_t)b * NTOK * 2304 + 1536 + d;
        for (int n = 0; n < NTOK; n++) {
            float vv = vcol[(size_t)n * 2304];
            #pragma unroll
            for (int a = 0; a < AGN; a++) av[a] = fmaf(s2[a][n], vv, av[a]);
        }
        #pragma unroll
        for (int a = 0; a < AGN; a++) agent_v[(size_t)(b*AGN + a)*DIMC + d] = av[a];
    }

    // agent-token blend (wave per a, softmax over d=768)
    {
        const int a = w;
        float tv[12];
        float m = -1e30f;
        #pragma unroll
        for (int i = 0; i < 12; i++) {
            int d = l + i * 64;
            tv[i] = tk1[(size_t)(b*AGN + a)*DIMC + d] + tk2[(size_t)(b*AGN + a)*DIMC + d];
            m = fmaxf(m, tv[i]);
        }
        m = wred_max(m);
        float ss = 0.f;
        #pragma unroll
        for (int i = 0; i < 12; i++) { tv[i] = expf(tv[i] - m); ss += tv[i]; }
        ss = wred_sum(ss);
        float inv = 1.f / ss;
        #pragma unroll
        for (int i = 0; i < 12; i++) {
            int d = l + i * 64;
            float ab = at_s[a*DIMC + d] * (tv[i] * inv + 2.f) * (1.f / 3.f);
            at_blend[(size_t)(b*AGN + a)*DIMC + d] = ab;
            out_at[(size_t)(b*AGN + a)*DIMC + d] = ab;
        }
    }
}

// ---------------------------------------------------------------------------
// Stage 2 (one block per batch):
//  q_attn = softmax_a(SCALE * q @ at_blend^T)
//  out_attn = q_attn @ agent_v
// ---------------------------------------------------------------------------
__global__ __launch_bounds__(256) void stage2_k(
    const float* __restrict__ qkv, const float* __restrict__ at_blend,
    const float* __restrict__ agent_v, float* __restrict__ out_attn)
{
    __shared__ float atb[AGN * DIMC];
    __shared__ float av[AGN * DIMC];
    __shared__ float qa[NTOK][AGN];

    const int b = blockIdx.x, tid = threadIdx.x;
    for (int i = tid; i < AGN * DIMC; i += 256) {
        atb[i] = at_blend[(size_t)b * 3072 + i];
        av[i]  = agent_v[(size_t)b * 3072 + i];
    }
    __syncthreads();

    if (tid < NTOK) {
        const float* qrow = qkv + (size_t)(b * NTOK + tid) * 2304;
        float s[AGN] = {0.f, 0.f, 0.f, 0.f};
        for (int d = 0; d < DIMC; d += 4) {
            float4 qv = *(const float4*)(qrow + d);
            #pragma unroll
            for (int a = 0; a < AGN; a++) {
                const float* ap = atb + a * DIMC + d;
                s[a] += ap[0]*qv.x + ap[1]*qv.y + ap[2]*qv.z + ap[3]*qv.w;
            }
        }
        #pragma unroll
        for (int a = 0; a < AGN; a++) s[a] *= SCALE_F;
        float m = fmaxf(fmaxf(s[0], s[1]), fmaxf(s[2], s[3]));
        float e[AGN]; float ss = 0.f;
        #pragma unroll
        for (int a = 0; a < AGN; a++) { e[a] = expf(s[a] - m); ss += e[a]; }
        float inv = 1.f / ss;
        #pragma unroll
        for (int a = 0; a < AGN; a++) qa[tid][a] = e[a] * inv;
    }
    __syncthreads();

    for (int n = 0; n < NTOK; n++) {
        const float p0 = qa[n][0], p1 = qa[n][1], p2 = qa[n][2], p3 = qa[n][3];
        for (int d = tid; d < DIMC; d += 256) {
            float o = p0*av[d] + p1*av[DIMC + d] + p2*av[2*DIMC + d] + p3*av[3*DIMC + d];
            out_attn[(size_t)(b * NTOK + n) * DIMC + d] = o;
        }
    }
}

// ---------------------------------------------------------------------------
extern "C" void kernel_launch(void* const* d_in, const int* in_sizes, int n_in,
                              void* d_out, int out_size, void* d_ws, size_t ws_size,
                              hipStream_t stream)
{
    const float* x     = (const float*)d_in[0];
    const float* attn1 = (const float*)d_in[1];
    const float* attn2 = (const float*)d_in[2];
    const float* tk1   = (const float*)d_in[3];
    const float* tk2   = (const float*)d_in[4];
    const float* Wqkv  = (const float*)d_in[5];
    const float* Wp1   = (const float*)d_in[6];
    const float* bp1   = (const float*)d_in[7];
    const float* Wp2   = (const float*)d_in[8];
    const float* bp2   = (const float*)d_in[9];
    const float* Wproj = (const float*)d_in[10];
    const float* bproj = (const float*)d_in[11];

    float* out     = (float*)d_out;                       // [128,196,768]
    float* out_rep = out + (size_t)NB * NTOK * DIMC;      // [128,1,4,196]
    float* out_at  = out_rep + (size_t)NB * AGN * NTOK;   // [128,1,4,768]

    float* ws = (float*)d_ws;
    size_t off = 0;
    float* qkv = ws + off;        off += (size_t)NB * NTOK * 2304;   // 57,802,752
    float* scratch = ws + off;    off += (size_t)NB * NTOK * DIMC;   // 19,267,584 (h1 aliases out_attn)
    float* h1 = scratch;          // [25088, 384] used before out_attn is written
    float* out_attn = scratch;    // [25088, 768]
    float* meanh1 = ws + off;     off += (size_t)NB * 384;
    float* agent_base = ws + off; off += (size_t)NB * 3072;
    float* at_blend = ws + off;   off += (size_t)NB * 3072;
    float* agent_v = ws + off;    off += (size_t)NB * 3072;
    // total: 78,299,136 floats = 313.2 MB

    dim3 blk(256);

    // 1. qkv = x @ W_qkv                       (25088 x 768 x 2304)
    sgemm_k<0><<<dim3(18, 196), blk, 0, stream>>>(x, DIMC, Wqkv, 2304, nullptr, qkv, 2304, DIMC);
    // 2. h1 = gelu(q @ W_pool1 + b1)           (25088 x 768 x 384), q = qkv cols [0,768)
    sgemm_k<2><<<dim3(3, 196), blk, 0, stream>>>(qkv, 2304, Wp1, 384, bp1, h1, 384, DIMC);
    // 3. meanh1 = mean_n(h1)
    mean_k<<<dim3(NB), dim3(384), 0, stream>>>(h1, meanh1);
    // 4. agent_base = meanh1 @ W_pool2 + b2    (128 x 384 x 3072)
    pool2_k<<<dim3(12, 16), blk, 0, stream>>>(meanh1, Wp2, bp2, agent_base);
    // 5. stage 1: scores/softmax/blends/agent_v
    stage1_k<<<dim3(NB), blk, 0, stream>>>(qkv, agent_base, attn1, attn2, tk1, tk2,
                                           agent_v, at_blend, out_rep, out_at);
    // 6. stage 2: q_attn + PV
    stage2_k<<<dim3(NB), blk, 0, stream>>>(qkv, at_blend, agent_v, out_attn);
    // 7. out = out_attn @ W_proj + b_proj      (25088 x 768 x 768)
    sgemm_k<1><<<dim3(6, 196), blk, 0, stream>>>(out_attn, DIMC, Wproj, DIMC, bproj, out, DIMC, DIMC);
}

// Round 2
// 576.025 us; speedup vs baseline: 3.3168x; 3.3168x over previous
//
#include <hip/hip_runtime.h>
#include <hip/hip_bf16.h>
#include <math.h>

// Problem constants
#define NB    128        // batch
#define NTOK  196        // tokens
#define DIMC  768        // channels
#define AGN   4          // agent tokens
#define SCALE_F 0.036084391824351614f   // 1/sqrt(768)

typedef __bf16  bf16x8  __attribute__((ext_vector_type(8)));
typedef float   f32x4   __attribute__((ext_vector_type(4)));
typedef unsigned short ushortx8 __attribute__((ext_vector_type(8)));
typedef unsigned short ushortx4 __attribute__((ext_vector_type(4)));

__device__ __forceinline__ unsigned short f2bf(float f) {
    union { float f; unsigned int u; } v; v.f = f;
    unsigned int r = v.u + 0x7fffu + ((v.u >> 16) & 1u);   // RNE
    return (unsigned short)(r >> 16);
}
__device__ __forceinline__ float bf2f(unsigned short u) {
    union { unsigned int u; float f; } v; v.u = ((unsigned int)u) << 16;
    return v.f;
}
__device__ __forceinline__ void load_lds16(const void* g, void* l) {
    __builtin_amdgcn_global_load_lds(
        (const __attribute__((address_space(1))) unsigned int*)g,
        (__attribute__((address_space(3))) unsigned int*)l, 16, 0, 0);
}

// ---------------------------------------------------------------------------
// bf16 MFMA GEMM, m97 structure: 128x128 tile, BK=32, 256 thr = 4 waves (2x2),
// each wave 64x64 = 4x4 fragments of 16x16x32. A[M][K] bf16, Bt[N][K] bf16.
// EPI: 0 = write bf16 C (no bias); 1 = f32 +bias; 2 = f32 +bias +exact GELU
// ---------------------------------------------------------------------------
template<int EPI>
__global__ __launch_bounds__(256) void gemm_bf16_k(
    const unsigned short* __restrict__ A, int lda,
    const unsigned short* __restrict__ Bt, int ldb,
    const float* __restrict__ bias,
    float* __restrict__ Cf, unsigned short* __restrict__ Cbf,
    int ldc, int K)
{
    __shared__ alignas(16) char lds[16384];   // A tile [128][32] bf16 @0, B tile @8192

    const int tid  = threadIdx.x;
    const int lane = tid & 63;
    const int wv   = tid >> 6;
    const int wr   = wv >> 1, wc = wv & 1;
    const int row0 = blockIdx.y * 128;
    const int col0 = blockIdx.x * 128;

    // staging: wave wv owns chunks c0,c1 (16 rows / 1024B each) of A and B tiles
    const int c0 = wv * 2, c1 = wv * 2 + 1;
    const int srow = lane >> 2;            // 0..15 within chunk
    const int skel = (lane & 3) << 3;      // k-elem offset 0/8/16/24
    const unsigned short* Ag0 = A  + (size_t)(row0 + c0*16 + srow) * lda + skel;
    const unsigned short* Ag1 = A  + (size_t)(row0 + c1*16 + srow) * lda + skel;
    const unsigned short* Bg0 = Bt + (size_t)(col0 + c0*16 + srow) * ldb + skel;
    const unsigned short* Bg1 = Bt + (size_t)(col0 + c1*16 + srow) * ldb + skel;
    char* lA0 = lds + c0 * 1024;
    char* lA1 = lds + c1 * 1024;
    char* lB0 = lds + 8192 + c0 * 1024;
    char* lB1 = lds + 8192 + c1 * 1024;

    f32x4 acc[4][4];
    #pragma unroll
    for (int m = 0; m < 4; m++)
        #pragma unroll
        for (int n = 0; n < 4; n++) acc[m][n] = (f32x4){0.f, 0.f, 0.f, 0.f};

    const int frow = lane & 15;            // fragment row/col index
    const int kgrp = (lane >> 4) * 16;     // byte offset of k-group (8 bf16)

    for (int bk = 0; bk < K; bk += 32) {
        __syncthreads();                   // previous tile's ds_reads complete
        load_lds16(Ag0 + bk, lA0);
        load_lds16(Ag1 + bk, lA1);
        load_lds16(Bg0 + bk, lB0);
        load_lds16(Bg1 + bk, lB1);
        __syncthreads();                   // vmcnt(0) drain + barrier: tile ready

        bf16x8 af[4], bf[4];
        #pragma unroll
        for (int m = 0; m < 4; m++)
            af[m] = *(const bf16x8*)(lds + ((wr*64 + m*16 + frow) * 64 + kgrp));
        #pragma unroll
        for (int n = 0; n < 4; n++)
            bf[n] = *(const bf16x8*)(lds + 8192 + ((wc*64 + n*16 + frow) * 64 + kgrp));
        #pragma unroll
        for (int m = 0; m < 4; m++)
            #pragma unroll
            for (int n = 0; n < 4; n++)
                acc[m][n] = __builtin_amdgcn_mfma_f32_16x16x32_bf16(af[m], bf[n], acc[m][n], 0, 0, 0);
    }

    // epilogue: C/D layout col=lane&15, row=(lane>>4)*4+r   [m89-verified]
    const int crow = (lane >> 4) << 2;
    #pragma unroll
    for (int n = 0; n < 4; n++) {
        const int col = col0 + wc*64 + n*16 + frow;
        const float bn = (EPI > 0) ? bias[col] : 0.f;
        #pragma unroll
        for (int m = 0; m < 4; m++) {
            #pragma unroll
            for (int r = 0; r < 4; r++) {
                const int row = row0 + wr*64 + m*16 + crow + r;
                float v = acc[m][n][r];
                if (EPI > 0) v += bn;
                if (EPI == 2) v = 0.5f * v * (1.f + erff(v * 0.7071067811865476f));
                if (EPI == 0) Cbf[(size_t)row * ldc + col] = f2bf(v);
                else          Cf [(size_t)row * ldc + col] = v;
            }
        }
    }
}

// ---------------------------------------------------------------------------
// fp32 -> bf16 straight convert, 8 elems/thread, grid sized exactly
// ---------------------------------------------------------------------------
__global__ __launch_bounds__(256) void conv_k(const float* __restrict__ in,
                                              unsigned short* __restrict__ out)
{
    const size_t i = ((size_t)blockIdx.x * 256 + threadIdx.x) * 8;
    float4 v0 = *(const float4*)(in + i);
    float4 v1 = *(const float4*)(in + i + 4);
    ushortx8 o;
    o[0]=f2bf(v0.x); o[1]=f2bf(v0.y); o[2]=f2bf(v0.z); o[3]=f2bf(v0.w);
    o[4]=f2bf(v1.x); o[5]=f2bf(v1.y); o[6]=f2bf(v1.z); o[7]=f2bf(v1.w);
    *(ushortx8*)(out + i) = o;
}

// ---------------------------------------------------------------------------
// W[K][N] f32 -> Wt[N][K] bf16 transpose-convert, 32x32 LDS tiles
// ---------------------------------------------------------------------------
__global__ __launch_bounds__(256) void tconv_k(const float* __restrict__ W,
                                               unsigned short* __restrict__ Wt,
                                               int K, int N)
{
    __shared__ float t[32][33];
    const int n0 = blockIdx.x * 32, k0 = blockIdx.y * 32;
    const int r = threadIdx.x >> 3;
    const int c = (threadIdx.x & 7) * 4;
    float4 v = *(const float4*)&W[(size_t)(k0 + r) * N + n0 + c];
    t[r][c] = v.x; t[r][c+1] = v.y; t[r][c+2] = v.z; t[r][c+3] = v.w;
    __syncthreads();
    ushortx4 o;
    o[0] = f2bf(t[c+0][r]); o[1] = f2bf(t[c+1][r]);
    o[2] = f2bf(t[c+2][r]); o[3] = f2bf(t[c+3][r]);
    *(ushortx4*)&Wt[(size_t)(n0 + r) * K + k0 + c] = o;
}

// ---------------------------------------------------------------------------
// Mean over tokens: mh[b][j] = mean_n h1[b,n,j]   (h1: [B*N, 384] f32)
// ---------------------------------------------------------------------------
__global__ __launch_bounds__(384) void mean_k(const float* __restrict__ h1,
                                              float* __restrict__ mh)
{
    const int b = blockIdx.x, j = threadIdx.x;
    const float* p = h1 + (size_t)b * NTOK * 384 + j;
    float s = 0.f;
    for (int n = 0; n < NTOK; n++) s += p[(size_t)n * 384];
    mh[b * 384 + j] = s * (1.f / (float)NTOK);
}

// ---------------------------------------------------------------------------
// agent_base[b][j] = mh[b,:] @ W2[:,j] + b2[j]   (all f32)
// ---------------------------------------------------------------------------
__global__ __launch_bounds__(256) void pool2_k(const float* __restrict__ mh,
                                               const float* __restrict__ W2,
                                               const float* __restrict__ b2,
                                               float* __restrict__ ab)
{
    __shared__ float rows[8][384];
    const int tid = threadIdx.x;
    const int bb0 = blockIdx.y * 8;
    for (int i = tid; i < 8 * 384; i += 256)
        rows[i / 384][i % 384] = mh[(size_t)(bb0 + i / 384) * 384 + (i % 384)];
    __syncthreads();

    const int j = blockIdx.x * 256 + tid;
    const float bj = b2[j];
    float acc[8];
    #pragma unroll
    for (int r = 0; r < 8; r++) acc[r] = bj;
    for (int k = 0; k < 384; k++) {
        float w = W2[(size_t)k * 3072 + j];
        #pragma unroll
        for (int r = 0; r < 8; r++) acc[r] = fmaf(rows[r][k], w, acc[r]);
    }
    #pragma unroll
    for (int r = 0; r < 8; r++) ab[(size_t)(bb0 + r) * 3072 + j] = acc[r];
}

// ---------------------------------------------------------------------------
__device__ __forceinline__ float wred_max(float v) {
    #pragma unroll
    for (int o = 32; o; o >>= 1) v = fmaxf(v, __shfl_xor(v, o, 64));
    return v;
}
__device__ __forceinline__ float wred_sum(float v) {
    #pragma unroll
    for (int o = 32; o; o >>= 1) v += __shfl_xor(v, o, 64);
    return v;
}

// ---------------------------------------------------------------------------
// Stage 1 (one block per batch), qkv now bf16 [B*N][2304]:
//  scores = softmax_n(SCALE * at @ k^T)  -> out_rep
//  pblend = scores * (softmax_n(attn1+attn2) + 2) / 3   [softmax over h==1 == 1]
//  agent_v = pblend @ v
//  at_blend = at * (softmax_d(tk1+tk2) + 2) / 3 -> out_at, ws
// ---------------------------------------------------------------------------
__global__ __launch_bounds__(256) void stage1_k(
    const unsigned short* __restrict__ qkv, const float* __restrict__ agent_base,
    const float* __restrict__ attn1, const float* __restrict__ attn2,
    const float* __restrict__ tk1, const float* __restrict__ tk2,
    float* __restrict__ agent_v, float* __restrict__ at_blend,
    float* __restrict__ out_rep, float* __restrict__ out_at)
{
    __shared__ float at_s[AGN * DIMC];
    __shared__ float sc[AGN][NTOK];
    __shared__ float s2[AGN][NTOK];

    const int b = blockIdx.x, tid = threadIdx.x;
    for (int i = tid; i < AGN * DIMC; i += 256) at_s[i] = agent_base[(size_t)b * 3072 + i];
    __syncthreads();

    if (tid < NTOK) {
        const unsigned short* krow = qkv + (size_t)(b * NTOK + tid) * 2304 + 768;
        float s[AGN] = {0.f, 0.f, 0.f, 0.f};
        for (int d = 0; d < DIMC; d += 8) {
            ushortx8 kv = *(const ushortx8*)(krow + d);
            float kf[8];
            #pragma unroll
            for (int e = 0; e < 8; e++) kf[e] = bf2f(kv[e]);
            #pragma unroll
            for (int a = 0; a < AGN; a++) {
                const float* ap = at_s + a * DIMC + d;
                float t = 0.f;
                #pragma unroll
                for (int e = 0; e < 8; e++) t = fmaf(ap[e], kf[e], t);
                s[a] += t;
            }
        }
        #pragma unroll
        for (int a = 0; a < AGN; a++) {
            sc[a][tid] = s[a] * SCALE_F;
            s2[a][tid] = attn1[(size_t)(b*AGN + a)*NTOK + tid] + attn2[(size_t)(b*AGN + a)*NTOK + tid];
        }
    }
    __syncthreads();

    const int w = tid >> 6, l = tid & 63;
    {
        const int a = w;
        float m = -1e30f;
        for (int i = l; i < NTOK; i += 64) m = fmaxf(m, sc[a][i]);
        m = wred_max(m);
        float ss = 0.f;
        for (int i = l; i < NTOK; i += 64) { float e = expf(sc[a][i] - m); sc[a][i] = e; ss += e; }
        ss = wred_sum(ss);
        float inv = 1.f / ss;
        for (int i = l; i < NTOK; i += 64) {
            float p = sc[a][i] * inv;
            sc[a][i] = p;
            out_rep[(size_t)(b*AGN + a)*NTOK + i] = p;
        }
        float m2 = -1e30f;
        for (int i = l; i < NTOK; i += 64) m2 = fmaxf(m2, s2[a][i]);
        m2 = wred_max(m2);
        float ss2 = 0.f;
        for (int i = l; i < NTOK; i += 64) { float e = expf(s2[a][i] - m2); s2[a][i] = e; ss2 += e; }
        ss2 = wred_sum(ss2);
        float inv2 = 1.f / ss2;
        for (int i = l; i < NTOK; i += 64)
            s2[a][i] = sc[a][i] * (s2[a][i] * inv2 + 2.f) * (1.f / 3.f);
    }
    __syncthreads();

    // agent_v[a][d] = sum_n pblend[a][n] * v[n][d]
    for (int d = tid; d < DIMC; d += 256) {
        float av[AGN] = {0.f, 0.f, 0.f, 0.f};
        const unsigned short* vcol = qkv + (size_t)b * NTOK * 2304 + 1536 + d;
        for (int n = 0; n < NTOK; n++) {
            float vv = bf2f(vcol[(size_t)n * 2304]);
            #pragma unroll
            for (int a = 0; a < AGN; a++) av[a] = fmaf(s2[a][n], vv, av[a]);
        }
        #pragma unroll
        for (int a = 0; a < AGN; a++) agent_v[(size_t)(b*AGN + a)*DIMC + d] = av[a];
    }

    // agent-token blend (wave per a, softmax over d=768)
    {
        const int a = w;
        float tv[12];
        float m = -1e30f;
        #pragma unroll
        for (int i = 0; i < 12; i++) {
            int d = l + i * 64;
            tv[i] = tk1[(size_t)(b*AGN + a)*DIMC + d] + tk2[(size_t)(b*AGN + a)*DIMC + d];
            m = fmaxf(m, tv[i]);
        }
        m = wred_max(m);
        float ss = 0.f;
        #pragma unroll
        for (int i = 0; i < 12; i++) { tv[i] = expf(tv[i] - m); ss += tv[i]; }
        ss = wred_sum(ss);
        float inv = 1.f / ss;
        #pragma unroll
        for (int i = 0; i < 12; i++) {
            int d = l + i * 64;
            float ab = at_s[a*DIMC + d] * (tv[i] * inv + 2.f) * (1.f / 3.f);
            at_blend[(size_t)(b*AGN + a)*DIMC + d] = ab;
            out_at[(size_t)(b*AGN + a)*DIMC + d] = ab;
        }
    }
}

// ---------------------------------------------------------------------------
// Stage 2 (one block per batch):
//  q_attn = softmax_a(SCALE * q @ at_blend^T);  out_attn_bf = q_attn @ agent_v
// ---------------------------------------------------------------------------
__global__ __launch_bounds__(256) void stage2_k(
    const unsigned short* __restrict__ qkv, const float* __restrict__ at_blend,
    const float* __restrict__ agent_v, unsigned short* __restrict__ out_attn_bf)
{
    __shared__ float atb[AGN * DIMC];
    __shared__ float av[AGN * DIMC];
    __shared__ float qa[NTOK][AGN];

    const int b = blockIdx.x, tid = threadIdx.x;
    for (int i = tid; i < AGN * DIMC; i += 256) {
        atb[i] = at_blend[(size_t)b * 3072 + i];
        av[i]  = agent_v[(size_t)b * 3072 + i];
    }
    __syncthreads();

    if (tid < NTOK) {
        const unsigned short* qrow = qkv + (size_t)(b * NTOK + tid) * 2304;
        float s[AGN] = {0.f, 0.f, 0.f, 0.f};
        for (int d = 0; d < DIMC; d += 8) {
            ushortx8 qv = *(const ushortx8*)(qrow + d);
            float qf[8];
            #pragma unroll
            for (int e = 0; e < 8; e++) qf[e] = bf2f(qv[e]);
            #pragma unroll
            for (int a = 0; a < AGN; a++) {
                const float* ap = atb + a * DIMC + d;
                float t = 0.f;
                #pragma unroll
                for (int e = 0; e < 8; e++) t = fmaf(ap[e], qf[e], t);
                s[a] += t;
            }
        }
        #pragma unroll
        for (int a = 0; a < AGN; a++) s[a] *= SCALE_F;
        float m = fmaxf(fmaxf(s[0], s[1]), fmaxf(s[2], s[3]));
        float e[AGN]; float ss = 0.f;
        #pragma unroll
        for (int a = 0; a < AGN; a++) { e[a] = expf(s[a] - m); ss += e[a]; }
        float inv = 1.f / ss;
        #pragma unroll
        for (int a = 0; a < AGN; a++) qa[tid][a] = e[a] * inv;
    }
    __syncthreads();

    for (int n = 0; n < NTOK; n++) {
        const float p0 = qa[n][0], p1 = qa[n][1], p2 = qa[n][2], p3 = qa[n][3];
        for (int d = tid; d < DIMC; d += 256) {
            float o = p0*av[d] + p1*av[DIMC + d] + p2*av[2*DIMC + d] + p3*av[3*DIMC + d];
            out_attn_bf[(size_t)(b * NTOK + n) * DIMC + d] = f2bf(o);
        }
    }
}

// ---------------------------------------------------------------------------
extern "C" void kernel_launch(void* const* d_in, const int* in_sizes, int n_in,
                              void* d_out, int out_size, void* d_ws, size_t ws_size,
                              hipStream_t stream)
{
    const float* x     = (const float*)d_in[0];
    const float* attn1 = (const float*)d_in[1];
    const float* attn2 = (const float*)d_in[2];
    const float* tk1   = (const float*)d_in[3];
    const float* tk2   = (const float*)d_in[4];
    const float* Wqkv  = (const float*)d_in[5];
    const float* Wp1   = (const float*)d_in[6];
    const float* bp1   = (const float*)d_in[7];
    const float* Wp2   = (const float*)d_in[8];
    const float* bp2   = (const float*)d_in[9];
    const float* Wproj = (const float*)d_in[10];
    const float* bproj = (const float*)d_in[11];

    float* out     = (float*)d_out;                       // [128,196,768] f32
    float* out_rep = out + (size_t)NB * NTOK * DIMC;      // [128,1,4,196]
    float* out_at  = out_rep + (size_t)NB * AGN * NTOK;   // [128,1,4,768]

    // workspace layout (bytes, all regions 256B-aligned by construction)
    char* ws = (char*)d_ws;
    unsigned short* qkvbf = (unsigned short*)ws;                      // [25088][2304] bf16, 115.6 MB
    ws += (size_t)NB * NTOK * 2304 * 2;
    unsigned short* abuf = (unsigned short*)ws;                       // xbf then out_attn_bf, 38.5 MB
    ws += (size_t)NB * NTOK * DIMC * 2;
    float* h1 = (float*)ws;                                           // [25088][384] f32, 38.5 MB
    ws += (size_t)NB * NTOK * 384 * 4;
    unsigned short* Wqkvt = (unsigned short*)ws;  ws += (size_t)2304 * 768 * 2;
    unsigned short* Wp1t  = (unsigned short*)ws;  ws += (size_t)384 * 768 * 2;
    unsigned short* Wprojt= (unsigned short*)ws;  ws += (size_t)768 * 768 * 2;
    float* meanh1     = (float*)ws;  ws += (size_t)NB * 384 * 4;
    float* agent_base = (float*)ws;  ws += (size_t)NB * 3072 * 4;
    float* at_blend   = (float*)ws;  ws += (size_t)NB * 3072 * 4;
    float* agent_v    = (float*)ws;  ws += (size_t)NB * 3072 * 4;
    // total ~= 203 MB (fits the previously-working 313 MB budget)

    unsigned short* xbf = abuf;
    unsigned short* out_attn_bf = abuf;

    dim3 blk(256);

    // 0a. x -> bf16  (19,267,584 elems / 8 per thread / 256 = 9408 blocks exact)
    conv_k<<<dim3(9408), blk, 0, stream>>>(x, xbf);
    // 0b. weight transpose-converts: W[K][N] f32 -> Wt[N][K] bf16
    tconv_k<<<dim3(2304/32, 768/32), blk, 0, stream>>>(Wqkv, Wqkvt, 768, 2304);
    tconv_k<<<dim3(384/32, 768/32), blk, 0, stream>>>(Wp1, Wp1t, 768, 384);
    tconv_k<<<dim3(768/32, 768/32), blk, 0, stream>>>(Wproj, Wprojt, 768, 768);

    // 1. qkvbf = bf16( xbf @ Wqkv )            (25088 x 768 x 2304), MFMA
    gemm_bf16_k<0><<<dim3(18, 196), blk, 0, stream>>>(xbf, DIMC, Wqkvt, DIMC,
                                                      nullptr, nullptr, qkvbf, 2304, DIMC);
    // 2. h1 = gelu(q @ Wp1 + b1)               (25088 x 768 x 384); q = qkvbf cols [0,768)
    gemm_bf16_k<2><<<dim3(3, 196), blk, 0, stream>>>(qkvbf, 2304, Wp1t, DIMC,
                                                     bp1, h1, nullptr, 384, DIMC);
    // 3. meanh1 = mean_n(h1)
    mean_k<<<dim3(NB), dim3(384), 0, stream>>>(h1, meanh1);
    // 4. agent_base = meanh1 @ W_pool2 + b2    (128 x 384 x 3072, f32)
    pool2_k<<<dim3(12, 16), blk, 0, stream>>>(meanh1, Wp2, bp2, agent_base);
    // 5. stage 1
    stage1_k<<<dim3(NB), blk, 0, stream>>>(qkvbf, agent_base, attn1, attn2, tk1, tk2,
                                           agent_v, at_blend, out_rep, out_at);
    // 6. stage 2 (writes bf16 out_attn, reusing xbf region — xbf dead after step 1)
    stage2_k<<<dim3(NB), blk, 0, stream>>>(qkvbf, at_blend, agent_v, out_attn_bf);
    // 7. out = out_attn @ W_proj + b_proj      (25088 x 768 x 768), MFMA
    gemm_bf16_k<1><<<dim3(6, 196), blk, 0, stream>>>(out_attn_bf, DIMC, Wprojt, DIMC,
                                                     bproj, out, nullptr, DIMC, DIMC);
}

// Round 5
// 494.888 us; speedup vs baseline: 3.8606x; 1.1639x over previous
//
#include <hip/hip_runtime.h>
#include <hip/hip_bf16.h>
#include <math.h>

// Problem constants
#define NB    128        // batch
#define NTOK  196        // tokens
#define DIMC  768        // channels
#define AGN   4          // agent tokens
#define SCALE_F 0.036084391824351614f   // 1/sqrt(768)

typedef __bf16  bf16x8  __attribute__((ext_vector_type(8)));
typedef float   f32x4   __attribute__((ext_vector_type(4)));
typedef unsigned short ushortx8 __attribute__((ext_vector_type(8)));
typedef unsigned short ushortx4 __attribute__((ext_vector_type(4)));

__device__ __forceinline__ unsigned short f2bf(float f) {
    union { float f; unsigned int u; } v; v.f = f;
    unsigned int r = v.u + 0x7fffu + ((v.u >> 16) & 1u);   // RNE
    return (unsigned short)(r >> 16);
}
__device__ __forceinline__ float bf2f(unsigned short u) {
    union { unsigned int u; float f; } v; v.u = ((unsigned int)u) << 16;
    return v.f;
}
__device__ __forceinline__ void load_lds16(const void* g, void* l) {
    __builtin_amdgcn_global_load_lds(
        (const __attribute__((address_space(1))) unsigned int*)g,
        (__attribute__((address_space(3))) unsigned int*)l, 16, 0, 0);
}

// ---------------------------------------------------------------------------
// bf16 MFMA GEMM, m97 structure: 128x128 tile, BK=32, 256 thr = 4 waves (2x2),
// each wave 64x64 = 4x4 fragments of 16x16x32. A[M][K] bf16, Bt[N][K] bf16.
// XCD-aware bijective block swizzle (m204) for L2 locality.
// EPI: 0 = write bf16 C (no bias); 1 = f32 +bias; 2 = f32 +bias +exact GELU
// ---------------------------------------------------------------------------
template<int EPI>
__global__ __launch_bounds__(256) void gemm_bf16_k(
    const unsigned short* __restrict__ A, int lda,
    const unsigned short* __restrict__ Bt, int ldb,
    const float* __restrict__ bias,
    float* __restrict__ Cf, unsigned short* __restrict__ Cbf,
    int ldc, int K)
{
    __shared__ alignas(16) char lds[16384];   // A tile [128][32] bf16 @0, B tile @8192

    // XCD-aware bijective swizzle: chunk the grid so each XCD gets
    // consecutive block ids (same A row-panel stays in one L2).
    const int nwg = gridDim.x * gridDim.y;
    const int id  = blockIdx.y * gridDim.x + blockIdx.x;
    const int q8  = nwg >> 3, r8 = nwg & 7;
    const int xcd = id & 7, off = id >> 3;
    const int nid = (xcd < r8 ? xcd * (q8 + 1) : r8 * (q8 + 1) + (xcd - r8) * q8) + off;
    const int bx = nid % gridDim.x, by = nid / gridDim.x;

    const int tid  = threadIdx.x;
    const int lane = tid & 63;
    const int wv   = tid >> 6;
    const int wr   = wv >> 1, wc = wv & 1;
    const int row0 = by * 128;
    const int col0 = bx * 128;

    // staging: wave wv owns chunks c0,c1 (16 rows / 1024B each) of A and B tiles
    const int c0 = wv * 2, c1 = wv * 2 + 1;
    const int srow = lane >> 2;            // 0..15 within chunk
    const int skel = (lane & 3) << 3;      // k-elem offset 0/8/16/24
    const unsigned short* Ag0 = A  + (size_t)(row0 + c0*16 + srow) * lda + skel;
    const unsigned short* Ag1 = A  + (size_t)(row0 + c1*16 + srow) * lda + skel;
    const unsigned short* Bg0 = Bt + (size_t)(col0 + c0*16 + srow) * ldb + skel;
    const unsigned short* Bg1 = Bt + (size_t)(col0 + c1*16 + srow) * ldb + skel;
    char* lA0 = lds + c0 * 1024;
    char* lA1 = lds + c1 * 1024;
    char* lB0 = lds + 8192 + c0 * 1024;
    char* lB1 = lds + 8192 + c1 * 1024;

    f32x4 acc[4][4];
    #pragma unroll
    for (int m = 0; m < 4; m++)
        #pragma unroll
        for (int n = 0; n < 4; n++) acc[m][n] = (f32x4){0.f, 0.f, 0.f, 0.f};

    const int frow = lane & 15;            // fragment row/col index
    const int kgrp = (lane >> 4) * 16;     // byte offset of k-group (8 bf16)

    for (int bk = 0; bk < K; bk += 32) {
        __syncthreads();                   // previous tile's ds_reads complete
        load_lds16(Ag0 + bk, lA0);
        load_lds16(Ag1 + bk, lA1);
        load_lds16(Bg0 + bk, lB0);
        load_lds16(Bg1 + bk, lB1);
        __syncthreads();                   // vmcnt(0) drain + barrier: tile ready

        bf16x8 af[4], bf[4];
        #pragma unroll
        for (int m = 0; m < 4; m++)
            af[m] = *(const bf16x8*)(lds + ((wr*64 + m*16 + frow) * 64 + kgrp));
        #pragma unroll
        for (int n = 0; n < 4; n++)
            bf[n] = *(const bf16x8*)(lds + 8192 + ((wc*64 + n*16 + frow) * 64 + kgrp));
        #pragma unroll
        for (int m = 0; m < 4; m++)
            #pragma unroll
            for (int n = 0; n < 4; n++)
                acc[m][n] = __builtin_amdgcn_mfma_f32_16x16x32_bf16(af[m], bf[n], acc[m][n], 0, 0, 0);
    }

    // epilogue: C/D layout col=lane&15, row=(lane>>4)*4+r   [m89-verified]
    const int crow = (lane >> 4) << 2;
    #pragma unroll
    for (int n = 0; n < 4; n++) {
        const int col = col0 + wc*64 + n*16 + frow;
        const float bn = (EPI > 0) ? bias[col] : 0.f;
        #pragma unroll
        for (int m = 0; m < 4; m++) {
            #pragma unroll
            for (int r = 0; r < 4; r++) {
                const int row = row0 + wr*64 + m*16 + crow + r;
                float v = acc[m][n][r];
                if (EPI > 0) v += bn;
                if (EPI == 2) v = 0.5f * v * (1.f + erff(v * 0.7071067811865476f));
                if (EPI == 0) Cbf[(size_t)row * ldc + col] = f2bf(v);
                else          Cf [(size_t)row * ldc + col] = v;
            }
        }
    }
}

// ---------------------------------------------------------------------------
// fp32 -> bf16 straight convert, 8 elems/thread
// ---------------------------------------------------------------------------
__global__ __launch_bounds__(256) void conv_k(const float* __restrict__ in,
                                              unsigned short* __restrict__ out)
{
    const size_t i = ((size_t)blockIdx.x * 256 + threadIdx.x) * 8;
    float4 v0 = *(const float4*)(in + i);
    float4 v1 = *(const float4*)(in + i + 4);
    ushortx8 o;
    o[0]=f2bf(v0.x); o[1]=f2bf(v0.y); o[2]=f2bf(v0.z); o[3]=f2bf(v0.w);
    o[4]=f2bf(v1.x); o[5]=f2bf(v1.y); o[6]=f2bf(v1.z); o[7]=f2bf(v1.w);
    *(ushortx8*)(out + i) = o;
}

// ---------------------------------------------------------------------------
// W[K][N] f32 -> Wt[N][K] bf16 transpose-convert, 32x32 LDS tiles
// ---------------------------------------------------------------------------
__global__ __launch_bounds__(256) void tconv_k(const float* __restrict__ W,
                                               unsigned short* __restrict__ Wt,
                                               int K, int N)
{
    __shared__ float t[32][33];
    const int n0 = blockIdx.x * 32, k0 = blockIdx.y * 32;
    const int r = threadIdx.x >> 3;
    const int c = (threadIdx.x & 7) * 4;
    float4 v = *(const float4*)&W[(size_t)(k0 + r) * N + n0 + c];
    t[r][c] = v.x; t[r][c+1] = v.y; t[r][c+2] = v.z; t[r][c+3] = v.w;
    __syncthreads();
    ushortx4 o;
    o[0] = f2bf(t[c+0][r]); o[1] = f2bf(t[c+1][r]);
    o[2] = f2bf(t[c+2][r]); o[3] = f2bf(t[c+3][r]);
    *(ushortx4*)&Wt[(size_t)(n0 + r) * K + k0 + c] = o;
}

// ---------------------------------------------------------------------------
// Mean over tokens: mh[b][j] = mean_n h1[b,n,j]; grid (128, 3), 128 thr
// 4-way unrolled accumulators break the serial add chain.
// ---------------------------------------------------------------------------
__global__ __launch_bounds__(128) void mean_k(const float* __restrict__ h1,
                                              float* __restrict__ mh)
{
    const int b = blockIdx.x;
    const int j = blockIdx.y * 128 + threadIdx.x;
    const float* p = h1 + (size_t)b * NTOK * 384 + j;
    float s0 = 0.f, s1 = 0.f, s2 = 0.f, s3 = 0.f;
    for (int n = 0; n < 196; n += 4) {          // 196 = 49*4 exact
        s0 += p[(size_t)(n+0) * 384];
        s1 += p[(size_t)(n+1) * 384];
        s2 += p[(size_t)(n+2) * 384];
        s3 += p[(size_t)(n+3) * 384];
    }
    mh[b * 384 + j] = (s0 + s1 + s2 + s3) * (1.f / 196.f);
}

// ---------------------------------------------------------------------------
// agent_base[b][j] = mh[b,:] @ W2[:,j] + b2[j]   (all f32)
// ---------------------------------------------------------------------------
__global__ __launch_bounds__(256) void pool2_k(const float* __restrict__ mh,
                                               const float* __restrict__ W2,
                                               const float* __restrict__ b2,
                                               float* __restrict__ ab)
{
    __shared__ float rows[8][384];
    const int tid = threadIdx.x;
    const int bb0 = blockIdx.y * 8;
    for (int i = tid; i < 8 * 384; i += 256)
        rows[i / 384][i % 384] = mh[(size_t)(bb0 + i / 384) * 384 + (i % 384)];
    __syncthreads();

    const int j = blockIdx.x * 256 + tid;
    const float bj = b2[j];
    float acc[8];
    #pragma unroll
    for (int r = 0; r < 8; r++) acc[r] = bj;
    #pragma unroll 4
    for (int k = 0; k < 384; k++) {
        float w = W2[(size_t)k * 3072 + j];
        #pragma unroll
        for (int r = 0; r < 8; r++) acc[r] = fmaf(rows[r][k], w, acc[r]);
    }
    #pragma unroll
    for (int r = 0; r < 8; r++) ab[(size_t)(bb0 + r) * 3072 + j] = acc[r];
}

// ---------------------------------------------------------------------------
__device__ __forceinline__ float wred_max(float v) {
    #pragma unroll
    for (int o = 32; o; o >>= 1) v = fmaxf(v, __shfl_xor(v, o, 64));
    return v;
}
__device__ __forceinline__ float wred_sum(float v) {
    #pragma unroll
    for (int o = 32; o; o >>= 1) v += __shfl_xor(v, o, 64);
    return v;
}

// ---------------------------------------------------------------------------
// Stage 1 (one block per batch), qkv bf16 [B*N][2304]:
//  scores = softmax_n(SCALE * at @ k^T)  -> out_rep
//  pblend = scores * (softmax_n(attn1+attn2) + 2) / 3   [softmax over h==1 == 1]
//  agent_v(bf16) = pblend @ v
//  at_blend = at * (softmax_d(tk1+tk2) + 2) / 3 -> out_at, ws
// Scores use quad-split dots: thread (tok,qo) computes 4 partial dots over a
// d-quarter; butterfly shfl over the quad yields all 4 full dots per thread.
// ---------------------------------------------------------------------------
__global__ __launch_bounds__(256) void stage1_k(
    const unsigned short* __restrict__ qkv, const float* __restrict__ agent_base,
    const float* __restrict__ attn1, const float* __restrict__ attn2,
    const float* __restrict__ tk1, const float* __restrict__ tk2,
    unsigned short* __restrict__ agent_v_bf, float* __restrict__ at_blend,
    float* __restrict__ out_rep, float* __restrict__ out_at)
{
    __shared__ float at_s[AGN * DIMC];
    __shared__ float sc[AGN][NTOK];
    __shared__ float s2[AGN][NTOK];

    const int b = blockIdx.x, tid = threadIdx.x;
    for (int i = tid; i < AGN * DIMC; i += 256) at_s[i] = agent_base[(size_t)b * 3072 + i];
    __syncthreads();

    // scores + external-attn sum: 784 (tok, quarter) work items
    for (int tt = tid; tt < NTOK * 4; tt += 256) {
        const int tok = tt >> 2, qo = tt & 3;
        const unsigned short* krow = qkv + (size_t)(b * NTOK + tok) * 2304 + 768 + qo * 192;
        float s[4] = {0.f, 0.f, 0.f, 0.f};
        for (int d = 0; d < 192; d += 8) {
            ushortx8 kv = *(const ushortx8*)(krow + d);
            float kf[8];
            #pragma unroll
            for (int e = 0; e < 8; e++) kf[e] = bf2f(kv[e]);
            #pragma unroll
            for (int a = 0; a < 4; a++) {
                const float* ap = at_s + a * DIMC + qo * 192 + d;
                float t = 0.f;
                #pragma unroll
                for (int e = 0; e < 8; e++) t = fmaf(ap[e], kf[e], t);
                s[a] += t;
            }
        }
        #pragma unroll
        for (int o = 1; o <= 2; o <<= 1)
            #pragma unroll
            for (int a = 0; a < 4; a++) s[a] += __shfl_xor(s[a], o, 64);
        sc[qo][tok] = s[qo] * SCALE_F;
        s2[qo][tok] = attn1[(size_t)(b*AGN + qo)*NTOK + tok] + attn2[(size_t)(b*AGN + qo)*NTOK + tok];
    }
    __syncthreads();

    // per-wave softmax over n (wave w handles agent a=w)
    const int w = tid >> 6, l = tid & 63;
    {
        const int a = w;
        float m = -1e30f;
        for (int i = l; i < NTOK; i += 64) m = fmaxf(m, sc[a][i]);
        m = wred_max(m);
        float ss = 0.f;
        for (int i = l; i < NTOK; i += 64) { float e = expf(sc[a][i] - m); sc[a][i] = e; ss += e; }
        ss = wred_sum(ss);
        float inv = 1.f / ss;
        for (int i = l; i < NTOK; i += 64) {
            float p = sc[a][i] * inv;
            sc[a][i] = p;
            out_rep[(size_t)(b*AGN + a)*NTOK + i] = p;
        }
        float m2 = -1e30f;
        for (int i = l; i < NTOK; i += 64) m2 = fmaxf(m2, s2[a][i]);
        m2 = wred_max(m2);
        float ss2 = 0.f;
        for (int i = l; i < NTOK; i += 64) { float e = expf(s2[a][i] - m2); s2[a][i] = e; ss2 += e; }
        ss2 = wred_sum(ss2);
        float inv2 = 1.f / ss2;
        for (int i = l; i < NTOK; i += 64)
            s2[a][i] = sc[a][i] * (s2[a][i] * inv2 + 2.f) * (1.f / 3.f);
    }
    __syncthreads();

    // agent_v[a][d] = sum_n pblend[a][n] * v[n][d]  -> bf16 (feeds AVW GEMM)
    for (int d = tid; d < DIMC; d += 256) {
        float av[AGN] = {0.f, 0.f, 0.f, 0.f};
        const unsigned short* vcol = qkv + (size_t)b * NTOK * 2304 + 1536 + d;
        for (int n = 0; n < NTOK; n++) {
            float vv = bf2f(vcol[(size_t)n * 2304]);
            #pragma unroll
            for (int a = 0; a < AGN; a++) av[a] = fmaf(s2[a][n], vv, av[a]);
        }
        #pragma unroll
        for (int a = 0; a < AGN; a++)
            agent_v_bf[(size_t)(b*AGN + a)*DIMC + d] = f2bf(av[a]);
    }

    // agent-token blend (wave per a, softmax over d=768)
    {
        const int a = w;
        float tv[12];
        float m = -1e30f;
        #pragma unroll
        for (int i = 0; i < 12; i++) {
            int d = l + i * 64;
            tv[i] = tk1[(size_t)(b*AGN + a)*DIMC + d] + tk2[(size_t)(b*AGN + a)*DIMC + d];
            m = fmaxf(m, tv[i]);
        }
        m = wred_max(m);
        float ss = 0.f;
        #pragma unroll
        for (int i = 0; i < 12; i++) { tv[i] = expf(tv[i] - m); ss += tv[i]; }
        ss = wred_sum(ss);
        float inv = 1.f / ss;
        #pragma unroll
        for (int i = 0; i < 12; i++) {
            int d = l + i * 64;
            float ab = at_s[a*DIMC + d] * (tv[i] * inv + 2.f) * (1.f / 3.f);
            at_blend[(size_t)(b*AGN + a)*DIMC + d] = ab;
            out_at[(size_t)(b*AGN + a)*DIMC + d] = ab;
        }
    }
}

// ---------------------------------------------------------------------------
// Stage 2, grid (4 token-chunks, 128 batches):
//  q_attn = softmax_a(SCALE * q @ at_blend^T)
//  out[b,n,:] = sum_a q_attn[n,a] * AVW[b,a,:]      (bias already in AVW;
//  proj GEMM eliminated because sum_a q_attn == 1)
// Quad-split dots: thread (tok,qo) loads a d-quarter of q once, computes 4
// partial dots, butterfly-shfl gives all 4 full dots -> local softmax.
// ---------------------------------------------------------------------------
__global__ __launch_bounds__(256) void stage2_k(
    const unsigned short* __restrict__ qkv, const float* __restrict__ at_blend,
    const float* __restrict__ avw, float* __restrict__ out)
{
    __shared__ float atb[AGN * DIMC];
    __shared__ float aw[AGN * DIMC];
    __shared__ float qa[49][AGN];

    const int b = blockIdx.y, chunk = blockIdx.x, tid = threadIdx.x;
    for (int i = tid; i < AGN * DIMC; i += 256) {
        atb[i] = at_blend[(size_t)b * 3072 + i];
        aw[i]  = avw[(size_t)b * 3072 + i];
    }
    __syncthreads();

    if (tid < 196) {
        const int tl = tid >> 2;             // local token 0..48
        const int qo = tid & 3;              // d-quarter
        const int tok = chunk * 49 + tl;
        const unsigned short* qrow = qkv + (size_t)(b * NTOK + tok) * 2304 + qo * 192;
        float s[4] = {0.f, 0.f, 0.f, 0.f};
        for (int d = 0; d < 192; d += 8) {
            ushortx8 qv = *(const ushortx8*)(qrow + d);
            float qf[8];
            #pragma unroll
            for (int e = 0; e < 8; e++) qf[e] = bf2f(qv[e]);
            #pragma unroll
            for (int a = 0; a < 4; a++) {
                const float* ap = atb + a * DIMC + qo * 192 + d;
                float t = 0.f;
                #pragma unroll
                for (int e = 0; e < 8; e++) t = fmaf(ap[e], qf[e], t);
                s[a] += t;
            }
        }
        #pragma unroll
        for (int o = 1; o <= 2; o <<= 1)
            #pragma unroll
            for (int a = 0; a < 4; a++) s[a] += __shfl_xor(s[a], o, 64);
        #pragma unroll
        for (int a = 0; a < 4; a++) s[a] *= SCALE_F;
        float m = fmaxf(fmaxf(s[0], s[1]), fmaxf(s[2], s[3]));
        float e[AGN]; float ss = 0.f;
        #pragma unroll
        for (int a = 0; a < 4; a++) { e[a] = expf(s[a] - m); ss += e[a]; }
        qa[tl][qo] = e[qo] / ss;
    }
    __syncthreads();

    for (int nn = 0; nn < 49; nn++) {
        const float p0 = qa[nn][0], p1 = qa[nn][1], p2 = qa[nn][2], p3 = qa[nn][3];
        const size_t rowo = (size_t)(b * NTOK + chunk * 49 + nn) * DIMC;
        for (int d = tid; d < DIMC; d += 256) {
            out[rowo + d] = p0*aw[d] + p1*aw[DIMC + d] + p2*aw[2*DIMC + d] + p3*aw[3*DIMC + d];
        }
    }
}

// ---------------------------------------------------------------------------
extern "C" void kernel_launch(void* const* d_in, const int* in_sizes, int n_in,
                              void* d_out, int out_size, void* d_ws, size_t ws_size,
                              hipStream_t stream)
{
    const float* x     = (const float*)d_in[0];
    const float* attn1 = (const float*)d_in[1];
    const float* attn2 = (const float*)d_in[2];
    const float* tk1   = (const float*)d_in[3];
    const float* tk2   = (const float*)d_in[4];
    const float* Wqkv  = (const float*)d_in[5];
    const float* Wp1   = (const float*)d_in[6];
    const float* bp1   = (const float*)d_in[7];
    const float* Wp2   = (const float*)d_in[8];
    const float* bp2   = (const float*)d_in[9];
    const float* Wproj = (const float*)d_in[10];
    const float* bproj = (const float*)d_in[11];

    float* out     = (float*)d_out;                       // [128,196,768] f32
    float* out_rep = out + (size_t)NB * NTOK * DIMC;      // [128,1,4,196]
    float* out_at  = out_rep + (size_t)NB * AGN * NTOK;   // [128,1,4,768]

    char* ws = (char*)d_ws;
    unsigned short* qkvbf = (unsigned short*)ws;                      // [25088][2304] bf16
    ws += (size_t)NB * NTOK * 2304 * 2;
    unsigned short* xbf = (unsigned short*)ws;                        // [25088][768] bf16
    ws += (size_t)NB * NTOK * DIMC * 2;
    float* h1 = (float*)ws;                                           // [25088][384] f32
    ws += (size_t)NB * NTOK * 384 * 4;
    unsigned short* Wqkvt = (unsigned short*)ws;  ws += (size_t)2304 * 768 * 2;
    unsigned short* Wp1t  = (unsigned short*)ws;  ws += (size_t)384 * 768 * 2;
    unsigned short* Wprojt= (unsigned short*)ws;  ws += (size_t)768 * 768 * 2;
    float* meanh1     = (float*)ws;  ws += (size_t)NB * 384 * 4;
    float* agent_base = (float*)ws;  ws += (size_t)NB * 3072 * 4;
    float* at_blend   = (float*)ws;  ws += (size_t)NB * 3072 * 4;
    unsigned short* agent_v_bf = (unsigned short*)ws;  ws += (size_t)NB * AGN * DIMC * 2;
    float* AVW        = (float*)ws;  ws += (size_t)NB * AGN * DIMC * 4;   // [512][768] f32
    // total ~= 204 MB

    dim3 blk(256);

    // 0a. x -> bf16
    conv_k<<<dim3(9408), blk, 0, stream>>>(x, xbf);
    // 0b. weight transpose-converts: W[K][N] f32 -> Wt[N][K] bf16
    tconv_k<<<dim3(2304/32, 768/32), blk, 0, stream>>>(Wqkv, Wqkvt, 768, 2304);
    tconv_k<<<dim3(384/32, 768/32), blk, 0, stream>>>(Wp1, Wp1t, 768, 384);
    tconv_k<<<dim3(768/32, 768/32), blk, 0, stream>>>(Wproj, Wprojt, 768, 768);

    // 1. qkvbf = bf16( xbf @ Wqkv )            (25088 x 768 x 2304), MFMA
    gemm_bf16_k<0><<<dim3(18, 196), blk, 0, stream>>>(xbf, DIMC, Wqkvt, DIMC,
                                                      nullptr, nullptr, qkvbf, 2304, DIMC);
    // 2. h1 = gelu(q @ Wp1 + b1)               (25088 x 768 x 384)
    gemm_bf16_k<2><<<dim3(3, 196), blk, 0, stream>>>(qkvbf, 2304, Wp1t, DIMC,
                                                     bp1, h1, nullptr, 384, DIMC);
    // 3. meanh1 = mean_n(h1)
    mean_k<<<dim3(NB, 3), dim3(128), 0, stream>>>(h1, meanh1);
    // 4. agent_base = meanh1 @ W_pool2 + b2    (128 x 384 x 3072, f32)
    pool2_k<<<dim3(12, 16), blk, 0, stream>>>(meanh1, Wp2, bp2, agent_base);
    // 5. stage 1: scores/softmax/blends/agent_v(bf16)
    stage1_k<<<dim3(NB), blk, 0, stream>>>(qkvbf, agent_base, attn1, attn2, tk1, tk2,
                                           agent_v_bf, at_blend, out_rep, out_at);
    // 6. AVW = agent_v @ W_proj + b_proj       (512 x 768 x 768, MFMA) — proj
    //    GEMM collapsed through q_attn (softmax rows sum to 1, bias folds in)
    gemm_bf16_k<1><<<dim3(6, 4), blk, 0, stream>>>(agent_v_bf, DIMC, Wprojt, DIMC,
                                                   bproj, AVW, nullptr, DIMC, DIMC);
    // 7. stage 2: q_attn softmax + out = q_attn @ AVW (writes d_out directly)
    stage2_k<<<dim3(4, NB), blk, 0, stream>>>(qkvbf, at_blend, AVW, out);
}

// Round 11
// 494.382 us; speedup vs baseline: 3.8646x; 1.0010x over previous
//
#include <hip/hip_runtime.h>
#include <hip/hip_bf16.h>
#include <math.h>

// Problem constants
#define NB    128        // batch
#define NTOK  196        // tokens
#define DIMC  768        // channels
#define AGN   4          // agent tokens
#define NCHUNK 7         // n-split for agent_v / stage2 (196 = 7*28)
#define SCALE_F 0.036084391824351614f   // 1/sqrt(768)

typedef __bf16  bf16x8  __attribute__((ext_vector_type(8)));
typedef float   f32x4   __attribute__((ext_vector_type(4)));
typedef unsigned short ushortx8 __attribute__((ext_vector_type(8)));
typedef unsigned short ushortx4 __attribute__((ext_vector_type(4)));

__device__ __forceinline__ unsigned short f2bf(float f) {
    union { float f; unsigned int u; } v; v.f = f;
    unsigned int r = v.u + 0x7fffu + ((v.u >> 16) & 1u);   // RNE
    return (unsigned short)(r >> 16);
}
__device__ __forceinline__ float bf2f(unsigned short u) {
    union { unsigned int u; float f; } v; v.u = ((unsigned int)u) << 16;
    return v.f;
}
__device__ __forceinline__ void load_lds16(const void* g, void* l) {
    __builtin_amdgcn_global_load_lds(
        (const __attribute__((address_space(1))) unsigned int*)g,
        (__attribute__((address_space(3))) unsigned int*)l, 16, 0, 0);
}

// ---------------------------------------------------------------------------
// bf16 MFMA GEMM, m97 structure: 128x128 tile, BK=32, 256 thr = 4 waves (2x2),
// each wave 64x64 = 4x4 fragments of 16x16x32. A[M][K] bf16, Bt[N][K] bf16.
// XCD-aware bijective block swizzle (m204): FETCH 187->91 MB measured (R5).
// EPI: 0 = write bf16 C (no bias); 1 = f32 +bias; 2 = f32 +bias +exact GELU
// ---------------------------------------------------------------------------
template<int EPI>
__global__ __launch_bounds__(256) void gemm_bf16_k(
    const unsigned short* __restrict__ A, int lda,
    const unsigned short* __restrict__ Bt, int ldb,
    const float* __restrict__ bias,
    float* __restrict__ Cf, unsigned short* __restrict__ Cbf,
    int ldc, int K)
{
    __shared__ alignas(16) char lds[16384];   // A tile [128][32] bf16 @0, B tile @8192

    const int nwg = gridDim.x * gridDim.y;
    const int id  = blockIdx.y * gridDim.x + blockIdx.x;
    const int q8  = nwg >> 3, r8 = nwg & 7;
    const int xcd = id & 7, off = id >> 3;
    const int nid = (xcd < r8 ? xcd * (q8 + 1) : r8 * (q8 + 1) + (xcd - r8) * q8) + off;
    const int bx = nid % gridDim.x, by = nid / gridDim.x;

    const int tid  = threadIdx.x;
    const int lane = tid & 63;
    const int wv   = tid >> 6;
    const int wr   = wv >> 1, wc = wv & 1;
    const int row0 = by * 128;
    const int col0 = bx * 128;

    const int c0 = wv * 2, c1 = wv * 2 + 1;
    const int srow = lane >> 2;            // 0..15 within chunk
    const int skel = (lane & 3) << 3;      // k-elem offset 0/8/16/24
    const unsigned short* Ag0 = A  + (size_t)(row0 + c0*16 + srow) * lda + skel;
    const unsigned short* Ag1 = A  + (size_t)(row0 + c1*16 + srow) * lda + skel;
    const unsigned short* Bg0 = Bt + (size_t)(col0 + c0*16 + srow) * ldb + skel;
    const unsigned short* Bg1 = Bt + (size_t)(col0 + c1*16 + srow) * ldb + skel;
    char* lA0 = lds + c0 * 1024;
    char* lA1 = lds + c1 * 1024;
    char* lB0 = lds + 8192 + c0 * 1024;
    char* lB1 = lds + 8192 + c1 * 1024;

    f32x4 acc[4][4];
    #pragma unroll
    for (int m = 0; m < 4; m++)
        #pragma unroll
        for (int n = 0; n < 4; n++) acc[m][n] = (f32x4){0.f, 0.f, 0.f, 0.f};

    const int frow = lane & 15;            // fragment row/col index
    const int kgrp = (lane >> 4) * 16;     // byte offset of k-group (8 bf16)

    for (int bk = 0; bk < K; bk += 32) {
        __syncthreads();
        load_lds16(Ag0 + bk, lA0);
        load_lds16(Ag1 + bk, lA1);
        load_lds16(Bg0 + bk, lB0);
        load_lds16(Bg1 + bk, lB1);
        __syncthreads();

        bf16x8 af[4], bf[4];
        #pragma unroll
        for (int m = 0; m < 4; m++)
            af[m] = *(const bf16x8*)(lds + ((wr*64 + m*16 + frow) * 64 + kgrp));
        #pragma unroll
        for (int n = 0; n < 4; n++)
            bf[n] = *(const bf16x8*)(lds + 8192 + ((wc*64 + n*16 + frow) * 64 + kgrp));
        #pragma unroll
        for (int m = 0; m < 4; m++)
            #pragma unroll
            for (int n = 0; n < 4; n++)
                acc[m][n] = __builtin_amdgcn_mfma_f32_16x16x32_bf16(af[m], bf[n], acc[m][n], 0, 0, 0);
    }

    // epilogue: C/D layout col=lane&15, row=(lane>>4)*4+r   [m89-verified]
    const int crow = (lane >> 4) << 2;
    #pragma unroll
    for (int n = 0; n < 4; n++) {
        const int col = col0 + wc*64 + n*16 + frow;
        const float bn = (EPI > 0) ? bias[col] : 0.f;
        #pragma unroll
        for (int m = 0; m < 4; m++) {
            #pragma unroll
            for (int r = 0; r < 4; r++) {
                const int row = row0 + wr*64 + m*16 + crow + r;
                float v = acc[m][n][r];
                if (EPI > 0) v += bn;
                if (EPI == 2) v = 0.5f * v * (1.f + erff(v * 0.7071067811865476f));
                if (EPI == 0) Cbf[(size_t)row * ldc + col] = f2bf(v);
                else          Cf [(size_t)row * ldc + col] = v;
            }
        }
    }
}

// ---------------------------------------------------------------------------
// fp32 -> bf16 straight convert, 8 elems/thread
// ---------------------------------------------------------------------------
__global__ __launch_bounds__(256) void conv_k(const float* __restrict__ in,
                                              unsigned short* __restrict__ out)
{
    const size_t i = ((size_t)blockIdx.x * 256 + threadIdx.x) * 8;
    float4 v0 = *(const float4*)(in + i);
    float4 v1 = *(const float4*)(in + i + 4);
    ushortx8 o;
    o[0]=f2bf(v0.x); o[1]=f2bf(v0.y); o[2]=f2bf(v0.z); o[3]=f2bf(v0.w);
    o[4]=f2bf(v1.x); o[5]=f2bf(v1.y); o[6]=f2bf(v1.z); o[7]=f2bf(v1.w);
    *(ushortx8*)(out + i) = o;
}

// ---------------------------------------------------------------------------
// W[K][N] f32 -> Wt[N][K] bf16 transpose-convert, 32x32 LDS tiles
// ---------------------------------------------------------------------------
__global__ __launch_bounds__(256) void tconv_k(const float* __restrict__ W,
                                               unsigned short* __restrict__ Wt,
                                               int K, int N)
{
    __shared__ float t[32][33];
    const int n0 = blockIdx.x * 32, k0 = blockIdx.y * 32;
    const int r = threadIdx.x >> 3;
    const int c = (threadIdx.x & 7) * 4;
    float4 v = *(const float4*)&W[(size_t)(k0 + r) * N + n0 + c];
    t[r][c] = v.x; t[r][c+1] = v.y; t[r][c+2] = v.z; t[r][c+3] = v.w;
    __syncthreads();
    ushortx4 o;
    o[0] = f2bf(t[c+0][r]); o[1] = f2bf(t[c+1][r]);
    o[2] = f2bf(t[c+2][r]); o[3] = f2bf(t[c+3][r]);
    *(ushortx4*)&Wt[(size_t)(n0 + r) * K + k0 + c] = o;
}

// ---------------------------------------------------------------------------
// Mean over tokens: mh[b][j] = mean_n h1[b,n,j]; grid (128, 3), 128 thr
// ---------------------------------------------------------------------------
__global__ __launch_bounds__(128) void mean_k(const float* __restrict__ h1,
                                              float* __restrict__ mh)
{
    const int b = blockIdx.x;
    const int j = blockIdx.y * 128 + threadIdx.x;
    const float* p = h1 + (size_t)b * NTOK * 384 + j;
    float s0 = 0.f, s1 = 0.f, s2 = 0.f, s3 = 0.f;
    for (int n = 0; n < 196; n += 4) {
        s0 += p[(size_t)(n+0) * 384];
        s1 += p[(size_t)(n+1) * 384];
        s2 += p[(size_t)(n+2) * 384];
        s3 += p[(size_t)(n+3) * 384];
    }
    mh[b * 384 + j] = (s0 + s1 + s2 + s3) * (1.f / 196.f);
}

// ---------------------------------------------------------------------------
// agent_base[b][j] = mh[b,:] @ W2[:,j] + b2[j]   (all f32)
// ---------------------------------------------------------------------------
__global__ __launch_bounds__(256) void pool2_k(const float* __restrict__ mh,
                                               const float* __restrict__ W2,
                                               const float* __restrict__ b2,
                                               float* __restrict__ ab)
{
    __shared__ float rows[8][384];
    const int tid = threadIdx.x;
    const int bb0 = blockIdx.y * 8;
    for (int i = tid; i < 8 * 384; i += 256)
        rows[i / 384][i % 384] = mh[(size_t)(bb0 + i / 384) * 384 + (i % 384)];
    __syncthreads();

    const int j = blockIdx.x * 256 + tid;
    const float bj = b2[j];
    float acc[8];
    #pragma unroll
    for (int r = 0; r < 8; r++) acc[r] = bj;
    #pragma unroll 4
    for (int k = 0; k < 384; k++) {
        float w = W2[(size_t)k * 3072 + j];
        #pragma unroll
        for (int r = 0; r < 8; r++) acc[r] = fmaf(rows[r][k], w, acc[r]);
    }
    #pragma unroll
    for (int r = 0; r < 8; r++) ab[(size_t)(bb0 + r) * 3072 + j] = acc[r];
}

// ---------------------------------------------------------------------------
__device__ __forceinline__ float wred_max(float v) {
    #pragma unroll
    for (int o = 32; o; o >>= 1) v = fmaxf(v, __shfl_xor(v, o, 64));
    return v;
}
__device__ __forceinline__ float wred_sum(float v) {
    #pragma unroll
    for (int o = 32; o; o >>= 1) v += __shfl_xor(v, o, 64);
    return v;
}

// ---------------------------------------------------------------------------
// s1a (one block per batch): scores/softmaxes/blends; agent_v moved to s1b.
//  scores = softmax_n(SCALE * at @ k^T)  -> out_rep
//  pblend = scores * (softmax_n(attn1+attn2) + 2) / 3 -> ws (feeds s1b)
//  at_blend = at * (softmax_d(tk1+tk2) + 2) / 3 -> out_at, ws
// ---------------------------------------------------------------------------
__global__ __launch_bounds__(256) void s1a_k(
    const unsigned short* __restrict__ qkv, const float* __restrict__ agent_base,
    const float* __restrict__ attn1, const float* __restrict__ attn2,
    const float* __restrict__ tk1, const float* __restrict__ tk2,
    float* __restrict__ pblend, float* __restrict__ at_blend,
    float* __restrict__ out_rep, float* __restrict__ out_at)
{
    __shared__ float at_s[AGN * DIMC];
    __shared__ float sc[AGN][NTOK];
    __shared__ float s2[AGN][NTOK];

    const int b = blockIdx.x, tid = threadIdx.x;
    for (int i = tid; i < AGN * DIMC; i += 256) at_s[i] = agent_base[(size_t)b * 3072 + i];
    __syncthreads();

    // scores + external-attn sum: 784 (tok, quarter) work items, quad-split
    for (int tt = tid; tt < NTOK * 4; tt += 256) {
        const int tok = tt >> 2, qo = tt & 3;
        const unsigned short* krow = qkv + (size_t)(b * NTOK + tok) * 2304 + 768 + qo * 192;
        float s[4] = {0.f, 0.f, 0.f, 0.f};
        for (int d = 0; d < 192; d += 8) {
            ushortx8 kv = *(const ushortx8*)(krow + d);
            float kf[8];
            #pragma unroll
            for (int e = 0; e < 8; e++) kf[e] = bf2f(kv[e]);
            #pragma unroll
            for (int a = 0; a < 4; a++) {
                const float* ap = at_s + a * DIMC + qo * 192 + d;
                float t = 0.f;
                #pragma unroll
                for (int e = 0; e < 8; e++) t = fmaf(ap[e], kf[e], t);
                s[a] += t;
            }
        }
        #pragma unroll
        for (int o = 1; o <= 2; o <<= 1)
            #pragma unroll
            for (int a = 0; a < 4; a++) s[a] += __shfl_xor(s[a], o, 64);
        sc[qo][tok] = s[qo] * SCALE_F;
        s2[qo][tok] = attn1[(size_t)(b*AGN + qo)*NTOK + tok] + attn2[(size_t)(b*AGN + qo)*NTOK + tok];
    }
    __syncthreads();

    // per-wave softmax over n (wave w handles agent a=w)
    const int w = tid >> 6, l = tid & 63;
    {
        const int a = w;
        float m = -1e30f;
        for (int i = l; i < NTOK; i += 64) m = fmaxf(m, sc[a][i]);
        m = wred_max(m);
        float ss = 0.f;
        for (int i = l; i < NTOK; i += 64) { float e = expf(sc[a][i] - m); sc[a][i] = e; ss += e; }
        ss = wred_sum(ss);
        float inv = 1.f / ss;
        for (int i = l; i < NTOK; i += 64) {
            float p = sc[a][i] * inv;
            sc[a][i] = p;
            out_rep[(size_t)(b*AGN + a)*NTOK + i] = p;
        }
        float m2 = -1e30f;
        for (int i = l; i < NTOK; i += 64) m2 = fmaxf(m2, s2[a][i]);
        m2 = wred_max(m2);
        float ss2 = 0.f;
        for (int i = l; i < NTOK; i += 64) { float e = expf(s2[a][i] - m2); s2[a][i] = e; ss2 += e; }
        ss2 = wred_sum(ss2);
        float inv2 = 1.f / ss2;
        for (int i = l; i < NTOK; i += 64)
            pblend[(size_t)(b*AGN + a)*NTOK + i] =
                sc[a][i] * (s2[a][i] * inv2 + 2.f) * (1.f / 3.f);
    }

    // agent-token blend (wave per a, softmax over d=768)
    {
        const int a = w;
        float tv[12];
        float m = -1e30f;
        #pragma unroll
        for (int i = 0; i < 12; i++) {
            int d = l + i * 64;
            tv[i] = tk1[(size_t)(b*AGN + a)*DIMC + d] + tk2[(size_t)(b*AGN + a)*DIMC + d];
            m = fmaxf(m, tv[i]);
        }
        m = wred_max(m);
        float ss = 0.f;
        #pragma unroll
        for (int i = 0; i < 12; i++) { tv[i] = expf(tv[i] - m); ss += tv[i]; }
        ss = wred_sum(ss);
        float inv = 1.f / ss;
        #pragma unroll
        for (int i = 0; i < 12; i++) {
            int d = l + i * 64;
            float ab = at_s[a*DIMC + d] * (tv[i] * inv + 2.f) * (1.f / 3.f);
            at_blend[(size_t)(b*AGN + a)*DIMC + d] = ab;
            out_at[(size_t)(b*AGN + a)*DIMC + d] = ab;
        }
    }
}

// ---------------------------------------------------------------------------
// s1b: agent_v partials, n-split. grid (NCHUNK=7, NB). Block (j,b) handles
// n in [j*28, j*28+28); writes its own avpart[j][b][a][d] region (no races).
// 896 blocks -> ~3.5/CU, 28-iter inner loop (vs 196 serial before).
// ---------------------------------------------------------------------------
__global__ __launch_bounds__(256) void s1b_k(
    const unsigned short* __restrict__ qkv, const float* __restrict__ pblend,
    float* __restrict__ avpart)
{
    __shared__ float pb[AGN][28];
    const int j = blockIdx.x, b = blockIdx.y, tid = threadIdx.x;
    const int n0 = j * 28;
    if (tid < AGN * 28) {
        const int a = tid / 28, nn = tid % 28;
        pb[a][nn] = pblend[((size_t)b*AGN + a)*NTOK + n0 + nn];
    }
    __syncthreads();

    const unsigned short* vbase = qkv + (size_t)(b * NTOK + n0) * 2304 + 1536;
    #pragma unroll
    for (int dd = 0; dd < 3; dd++) {
        const int d = tid + dd * 256;
        const unsigned short* vp = vbase + d;
        float a0 = 0.f, a1 = 0.f, a2 = 0.f, a3 = 0.f;
        #pragma unroll
        for (int nn = 0; nn < 28; nn++) {
            float vv = bf2f(vp[(size_t)nn * 2304]);
            a0 = fmaf(pb[0][nn], vv, a0);
            a1 = fmaf(pb[1][nn], vv, a1);
            a2 = fmaf(pb[2][nn], vv, a2);
            a3 = fmaf(pb[3][nn], vv, a3);
        }
        float* op = avpart + (((size_t)j * NB + b) * AGN) * DIMC + d;
        op[0*DIMC] = a0; op[1*DIMC] = a1; op[2*DIMC] = a2; op[3*DIMC] = a3;
    }
}

// ---------------------------------------------------------------------------
// avred: sum 7 partials -> bf16 agent_v. 512*768 outputs, 4/thread, 384 blk.
// ---------------------------------------------------------------------------
__global__ __launch_bounds__(256) void avred_k(const float* __restrict__ avpart,
                                               unsigned short* __restrict__ avbf)
{
    const size_t i = ((size_t)blockIdx.x * 256 + threadIdx.x) * 4;
    float4 s = *(const float4*)(avpart + i);
    #pragma unroll
    for (int j = 1; j < NCHUNK; j++) {
        float4 t = *(const float4*)(avpart + (size_t)j * NB * AGN * DIMC + i);
        s.x += t.x; s.y += t.y; s.z += t.z; s.w += t.w;
    }
    ushortx4 o;
    o[0] = f2bf(s.x); o[1] = f2bf(s.y); o[2] = f2bf(s.z); o[3] = f2bf(s.w);
    *(ushortx4*)(avbf + i) = o;
}

// ---------------------------------------------------------------------------
// Stage 2, grid (NCHUNK=7 token-chunks, 128 batches), 28 tokens per chunk:
//  q_attn = softmax_a(SCALE * q @ at_blend^T)
//  out[b,n,:] = sum_a q_attn[n,a] * AVW[b,a,:]   (proj folded into AVW)
// ---------------------------------------------------------------------------
__global__ __launch_bounds__(256) void stage2_k(
    const unsigned short* __restrict__ qkv, const float* __restrict__ at_blend,
    const float* __restrict__ avw, float* __restrict__ out)
{
    __shared__ float atb[AGN * DIMC];
    __shared__ float aw[AGN * DIMC];
    __shared__ float qa[28][AGN];

    const int b = blockIdx.y, chunk = blockIdx.x, tid = threadIdx.x;
    for (int i = tid; i < AGN * DIMC; i += 256) {
        atb[i] = at_blend[(size_t)b * 3072 + i];
        aw[i]  = avw[(size_t)b * 3072 + i];
    }
    __syncthreads();

    if (tid < 112) {                        // 28 tokens x 4 quad-threads
        const int tl = tid >> 2;            // local token 0..27
        const int qo = tid & 3;             // d-quarter
        const int tok = chunk * 28 + tl;
        const unsigned short* qrow = qkv + (size_t)(b * NTOK + tok) * 2304 + qo * 192;
        float s[4] = {0.f, 0.f, 0.f, 0.f};
        for (int d = 0; d < 192; d += 8) {
            ushortx8 qv = *(const ushortx8*)(qrow + d);
            float qf[8];
            #pragma unroll
            for (int e = 0; e < 8; e++) qf[e] = bf2f(qv[e]);
            #pragma unroll
            for (int a = 0; a < 4; a++) {
                const float* ap = atb + a * DIMC + qo * 192 + d;
                float t = 0.f;
                #pragma unroll
                for (int e = 0; e < 8; e++) t = fmaf(ap[e], qf[e], t);
                s[a] += t;
            }
        }
        #pragma unroll
        for (int o = 1; o <= 2; o <<= 1)
            #pragma unroll
            for (int a = 0; a < 4; a++) s[a] += __shfl_xor(s[a], o, 64);
        #pragma unroll
        for (int a = 0; a < 4; a++) s[a] *= SCALE_F;
        float m = fmaxf(fmaxf(s[0], s[1]), fmaxf(s[2], s[3]));
        float e[AGN]; float ss = 0.f;
        #pragma unroll
        for (int a = 0; a < 4; a++) { e[a] = expf(s[a] - m); ss += e[a]; }
        qa[tl][qo] = e[qo] / ss;
    }
    __syncthreads();

    for (int nn = 0; nn < 28; nn++) {
        const float p0 = qa[nn][0], p1 = qa[nn][1], p2 = qa[nn][2], p3 = qa[nn][3];
        const size_t rowo = (size_t)(b * NTOK + chunk * 28 + nn) * DIMC;
        for (int d = tid; d < DIMC; d += 256) {
            out[rowo + d] = p0*aw[d] + p1*aw[DIMC + d] + p2*aw[2*DIMC + d] + p3*aw[3*DIMC + d];
        }
    }
}

// ---------------------------------------------------------------------------
extern "C" void kernel_launch(void* const* d_in, const int* in_sizes, int n_in,
                              void* d_out, int out_size, void* d_ws, size_t ws_size,
                              hipStream_t stream)
{
    const float* x     = (const float*)d_in[0];
    const float* attn1 = (const float*)d_in[1];
    const float* attn2 = (const float*)d_in[2];
    const float* tk1   = (const float*)d_in[3];
    const float* tk2   = (const float*)d_in[4];
    const float* Wqkv  = (const float*)d_in[5];
    const float* Wp1   = (const float*)d_in[6];
    const float* bp1   = (const float*)d_in[7];
    const float* Wp2   = (const float*)d_in[8];
    const float* bp2   = (const float*)d_in[9];
    const float* Wproj = (const float*)d_in[10];
    const float* bproj = (const float*)d_in[11];

    float* out     = (float*)d_out;                       // [128,196,768] f32
    float* out_rep = out + (size_t)NB * NTOK * DIMC;      // [128,1,4,196]
    float* out_at  = out_rep + (size_t)NB * AGN * NTOK;   // [128,1,4,768]

    char* ws = (char*)d_ws;
    unsigned short* qkvbf = (unsigned short*)ws;                      // [25088][2304] bf16
    ws += (size_t)NB * NTOK * 2304 * 2;
    unsigned short* xbf = (unsigned short*)ws;                        // [25088][768] bf16
    ws += (size_t)NB * NTOK * DIMC * 2;
    float* h1 = (float*)ws;                                           // [25088][384] f32
    ws += (size_t)NB * NTOK * 384 * 4;
    unsigned short* Wqkvt = (unsigned short*)ws;  ws += (size_t)2304 * 768 * 2;
    unsigned short* Wp1t  = (unsigned short*)ws;  ws += (size_t)384 * 768 * 2;
    unsigned short* Wprojt= (unsigned short*)ws;  ws += (size_t)768 * 768 * 2;
    float* meanh1     = (float*)ws;  ws += (size_t)NB * 384 * 4;
    float* agent_base = (float*)ws;  ws += (size_t)NB * 3072 * 4;
    float* at_blend   = (float*)ws;  ws += (size_t)NB * 3072 * 4;
    float* pblend     = (float*)ws;  ws += (size_t)NB * AGN * NTOK * 4;        // [128][4][196]
    float* avpart     = (float*)ws;  ws += (size_t)NCHUNK * NB * AGN * DIMC * 4; // [7][512][768]
    unsigned short* agent_v_bf = (unsigned short*)ws;  ws += (size_t)NB * AGN * DIMC * 2;
    float* AVW        = (float*)ws;  ws += (size_t)NB * AGN * DIMC * 4;        // [512][768] f32
    // total ~= 216 MB

    dim3 blk(256);

    // 0a. x -> bf16
    conv_k<<<dim3(9408), blk, 0, stream>>>(x, xbf);
    // 0b. weight transpose-converts: W[K][N] f32 -> Wt[N][K] bf16
    tconv_k<<<dim3(2304/32, 768/32), blk, 0, stream>>>(Wqkv, Wqkvt, 768, 2304);
    tconv_k<<<dim3(384/32, 768/32), blk, 0, stream>>>(Wp1, Wp1t, 768, 384);
    tconv_k<<<dim3(768/32, 768/32), blk, 0, stream>>>(Wproj, Wprojt, 768, 768);

    // 1. qkvbf = bf16( xbf @ Wqkv )            (25088 x 768 x 2304), MFMA
    gemm_bf16_k<0><<<dim3(18, 196), blk, 0, stream>>>(xbf, DIMC, Wqkvt, DIMC,
                                                      nullptr, nullptr, qkvbf, 2304, DIMC);
    // 2. h1 = gelu(q @ Wp1 + b1)               (25088 x 768 x 384)
    gemm_bf16_k<2><<<dim3(3, 196), blk, 0, stream>>>(qkvbf, 2304, Wp1t, DIMC,
                                                     bp1, h1, nullptr, 384, DIMC);
    // 3. meanh1 = mean_n(h1)
    mean_k<<<dim3(NB, 3), dim3(128), 0, stream>>>(h1, meanh1);
    // 4. agent_base = meanh1 @ W_pool2 + b2    (128 x 384 x 3072, f32)
    pool2_k<<<dim3(12, 16), blk, 0, stream>>>(meanh1, Wp2, bp2, agent_base);
    // 5a. scores/softmaxes/blends -> pblend, at_blend, out_rep, out_at
    s1a_k<<<dim3(NB), blk, 0, stream>>>(qkvbf, agent_base, attn1, attn2, tk1, tk2,
                                        pblend, at_blend, out_rep, out_at);
    // 5b. agent_v partials (n-split 7x, 896 blocks)
    s1b_k<<<dim3(NCHUNK, NB), blk, 0, stream>>>(qkvbf, pblend, avpart);
    // 5c. reduce partials -> bf16 agent_v
    avred_k<<<dim3(384), blk, 0, stream>>>(avpart, agent_v_bf);
    // 6. AVW = agent_v @ W_proj + b_proj       (512 x 768 x 768, MFMA)
    gemm_bf16_k<1><<<dim3(6, 4), blk, 0, stream>>>(agent_v_bf, DIMC, Wprojt, DIMC,
                                                   bproj, AVW, nullptr, DIMC, DIMC);
    // 7. stage 2: q_attn softmax + out = q_attn @ AVW (writes d_out directly)
    stage2_k<<<dim3(NCHUNK, NB), blk, 0, stream>>>(qkvbf, at_blend, AVW, out);
}